// Round 7
// baseline (158.041 us; speedup 1.0000x reference)
//
#include <hip/hip_runtime.h>
#include <hip/hip_bf16.h>
#include <math.h>

#define NB  32
#define NT  200
#define NTQ 50
#define NE  64
#define NP  128
#define NC  64
#define NU  36
#define NROW (NB * NTQ)   // 1600

typedef __attribute__((ext_vector_type(8))) short bf8;   // 8 bf16 in 4 VGPRs
typedef __attribute__((ext_vector_type(4))) short s4v;   // 4 bf16
typedef __attribute__((ext_vector_type(4))) float f4;

// ---- ws layout ----
// shorts: wm1f @0 (65536) | wm2f @65536 (32768) | wm3f @98304 (8192)
//         | w1f @106496 (6144)  -> 112640 shorts = 225280 B
// floats (byte offsets): kW @ 225280 (57600 f32, incl b1)
//                        w  @ 455680 (1600*200 f32 attention weights)
#define WM1F_OFF 0
#define WM2F_OFF 65536
#define WM3F_OFF 98304
#define W1F_OFF  106496
#define KW_BYTE  225280
#define W_BYTE   455680

#define ATTN_BLOCKS 416            // 32 b x 13 t-tiles
#define PACK_ELEMS  (65536 + 32768 + 8192)   // 106496
#define PACK_BLOCKS (PACK_ELEMS / 256)       // 416

__device__ __forceinline__ short f2bf(float x) {
    __hip_bfloat16 h = __float2bfloat16(x);
    return __builtin_bit_cast(short, h);
}
__device__ __forceinline__ float bf2f(short s) {
    unsigned u = ((unsigned)(unsigned short)s) << 16;
    return __builtin_bit_cast(float, u);
}

// ---------------------------------------------------------------------------
// Kernel 0: prep.
//   idx <  57600 : kW[row][u] = b1[u] + it[row] @ (W1b - W1c)   (f32)
//   next   6144  : w1f = [ (W1a+W1c) | W1d ] fragments (u padded to 48)
// grid = 249 blocks.
// ---------------------------------------------------------------------------
__global__ __launch_bounds__(256) void prep(
    const float* __restrict__ it, const float* __restrict__ W1,
    const float* __restrict__ b1,
    float* __restrict__ kW, short* __restrict__ w1f)
{
    int idx = blockIdx.x * 256 + threadIdx.x;
    if (idx < NROW * NU) {
        int u = idx % NU, row = idx / NU;
        const float* k = it + row * NE;
        float acc = b1[u];
        #pragma unroll 4
        for (int e = 0; e < NE; ++e)
            acc = fmaf(k[e], W1[(64 + e) * NU + u] - W1[(128 + e) * NU + u], acc);
        kW[idx] = acc;
        return;
    }
    idx -= NROW * NU;
    // w1f: 6144 elems, tile = nt*4 + ks, kk in [0,128)
    int i = idx & 7, lane = (idx >> 3) & 63, tile = idx >> 9;
    int ks = tile & 3, nt = tile >> 2;
    int kk = ks * 32 + 8 * (lane >> 4) + i;   // 0..127
    int n  = nt * 16 + (lane & 15);           // u in 0..47 (pad >=36 with 0)
    float v = 0.f;
    if (n < NU) {
        v = W1[(128 + kk) * NU + n];          // W1c (kk<64) or W1d (kk>=64)
        if (kk < 64) v += W1[kk * NU + n];    // + W1a
    }
    w1f[idx] = f2bf(v);
}

// ---------------------------------------------------------------------------
// Kernel 1: blocks [0,416): attention, block = (b, t-tile), inner loop tq.
//   Per wave: build aq once; loop tq (stride 4): ap = f2bf(q_bf16 * k),
//   12 MFMA, dice+W2 epilogue, 16-lane reduce, store w[b*50+tq][t0..t0+15].
// blocks [416,832): pack trunk weight fragments.
// ---------------------------------------------------------------------------
__device__ __forceinline__ void pack_frag(int j, const float* W, int N, int ksc, short* dst) {
    int i    = j & 7;
    int lane = (j >> 3) & 63;
    int tile = j >> 9;
    int ks = tile % ksc;
    int nt = tile / ksc;
    int k = ks * 32 + 8 * (lane >> 4) + i;
    int n = nt * 16 + (lane & 15);
    dst[j] = f2bf(W[k * N + n]);
}

struct AParams {
    const float *ub, *it, *kW, *W2, *b2, *da, *dm, *dv;
    const float *Wm1, *Wm2, *Wm3;
    const short *w1f;
    short *wm1f, *wm2f, *wm3f;
    float *w;      // [NROW][NT]
};

__global__ __launch_bounds__(256) void attn2(AParams P) {
    const int bid = blockIdx.x;
    const int tid = threadIdx.x;

    if (bid >= ATTN_BLOCKS) {                 // ---- pack path ----
        int j = (bid - ATTN_BLOCKS) * 256 + tid;
        if (j < 65536) { pack_frag(j, P.Wm1, 256, 8, P.wm1f); return; }
        j -= 65536;
        if (j < 32768) { pack_frag(j, P.Wm2, 128, 8, P.wm2f); return; }
        j -= 32768;
        pack_frag(j, P.Wm3, 64, 4, P.wm3f);
        return;
    }

    const int l = tid & 63, wv = tid >> 6;
    const int tt = bid % 13, b = bid / 13;
    const int t0 = tt * 16;
    const int ul = l & 15;

    // persistent B-fragments (q | q*k blocks): 8 x bf8 = 32 VGPR... per nt: 4
    const bf8* wf = (const bf8*)P.w1f;
    bf8 bfr[3][4];
    #pragma unroll
    for (int nt = 0; nt < 3; ++nt)
        #pragma unroll
        for (int ks = 0; ks < 4; ++ks)
            bfr[nt][ks] = wf[(nt * 4 + ks) * 64 + l];

    // A q-side fragments: built ONCE for this tile (rows t0..t0+15)
    int tA = t0 + ul; if (tA > NT - 1) tA = NT - 1;   // clamp; extra rows not stored
    bf8 aq[2];
    {
        const float* ubr = P.ub + ((size_t)b * NT + tA) * NE;
        #pragma unroll
        for (int ks = 0; ks < 2; ++ks) {
            int e0 = ks * 32 + 8 * (l >> 4);
            f4 u0 = *(const f4*)(ubr + e0);
            f4 u1 = *(const f4*)(ubr + e0 + 4);
            #pragma unroll
            for (int i = 0; i < 4; ++i) {
                aq[ks][i]     = f2bf(u0[i]);
                aq[ks][4 + i] = f2bf(u1[i]);
            }
        }
    }

    // per-u (output column) dice/W2 constants
    float dmv[3], drs[3], dav[3], w2v[3];
    #pragma unroll
    for (int nt = 0; nt < 3; ++nt) {
        int u = nt * 16 + ul;
        bool v = (u < NU);
        int uc = v ? u : (NU - 1);
        dmv[nt] = P.dm[uc];
        drs[nt] = rsqrtf(P.dv[uc] + 1e-6f);
        dav[nt] = P.da[uc];
        w2v[nt] = v ? P.W2[uc] : 0.f;
    }
    const float b2s = P.b2[0];
    const float* kwb = P.kW + (size_t)b * NTQ * NU;
    const float* itb = P.it + (size_t)b * NTQ * NE;

    for (int tq = wv; tq < NTQ; tq += 4) {
        // k vector (L1-resident) -> ap = bf16(q_bf16 * k)
        bf8 ap[2];
        {
            const float* itr = itb + tq * NE;
            #pragma unroll
            for (int ks = 0; ks < 2; ++ks) {
                int e0 = ks * 32 + 8 * (l >> 4);
                f4 v0 = *(const f4*)(itr + e0);
                f4 v1 = *(const f4*)(itr + e0 + 4);
                #pragma unroll
                for (int i = 0; i < 4; ++i) {
                    ap[ks][i]     = f2bf(bf2f(aq[ks][i])     * v0[i]);
                    ap[ks][4 + i] = f2bf(bf2f(aq[ks][4 + i]) * v1[i]);
                }
            }
        }
        // k-side projection (precomputed, incl b1)
        float kwv[3];
        #pragma unroll
        for (int nt = 0; nt < 3; ++nt) {
            int u = nt * 16 + ul;
            kwv[nt] = kwb[tq * NU + ((u < NU) ? u : (NU - 1))];
        }

        f4 acc[3];
        #pragma unroll
        for (int nt = 0; nt < 3; ++nt) { acc[nt][0]=0.f; acc[nt][1]=0.f; acc[nt][2]=0.f; acc[nt][3]=0.f; }
        #pragma unroll
        for (int nt = 0; nt < 3; ++nt) {
            acc[nt] = __builtin_amdgcn_mfma_f32_16x16x32_bf16(aq[0], bfr[nt][0], acc[nt], 0, 0, 0);
            acc[nt] = __builtin_amdgcn_mfma_f32_16x16x32_bf16(aq[1], bfr[nt][1], acc[nt], 0, 0, 0);
            acc[nt] = __builtin_amdgcn_mfma_f32_16x16x32_bf16(ap[0], bfr[nt][2], acc[nt], 0, 0, 0);
            acc[nt] = __builtin_amdgcn_mfma_f32_16x16x32_bf16(ap[1], bfr[nt][3], acc[nt], 0, 0, 0);
        }

        // dice + W2, reduce over u (16 lanes), store 4 rows as one f4
        float val[4];
        #pragma unroll
        for (int i = 0; i < 4; ++i) {
            float s = 0.f;
            #pragma unroll
            for (int nt = 0; nt < 3; ++nt) {
                float x = acc[nt][i] + kwv[nt];
                float z = (x - dmv[nt]) * drs[nt];
                float p = 1.f / (1.f + __expf(-z));
                s += x * (dav[nt] + p * (1.f - dav[nt])) * w2v[nt];
            }
            val[i] = s;
        }
        #pragma unroll
        for (int i = 0; i < 4; ++i) {
            val[i] += __shfl_xor(val[i], 1);
            val[i] += __shfl_xor(val[i], 2);
            val[i] += __shfl_xor(val[i], 4);
            val[i] += __shfl_xor(val[i], 8);
        }
        int trow = t0 + 4 * (l >> 4);
        if (ul == 0 && trow < NT) {
            f4 o;
            o[0] = val[0] + b2s; o[1] = val[1] + b2s;
            o[2] = val[2] + b2s; o[3] = val[3] + b2s;
            *(f4*)&P.w[((size_t)b * NTQ + tq) * NT + trow] = o;
        }
    }
}

// ---------------------------------------------------------------------------
// Kernel 2: trunk. 100 blocks x 16 rows. Staging: interest = w @ ub (scalar),
// BN1, plus bn1(profile||context) cols; then 3-layer MFMA MLP.
// ---------------------------------------------------------------------------
struct TParams {
    const float *w, *ub, *up, *cx;
    const short *wm1f, *wm2f, *wm3f;
    const float *bn1_g, *bn1_b, *bn1_m, *bn1_v;
    const float *bm1, *bm2, *bm3;
    const float *bn2_g, *bn2_b, *bn2_m, *bn2_v;
    const float *bn3_g, *bn3_b, *bn3_m, *bn3_v;
    float* out;
};

#define LSTR 264   // bf16 row stride for Ha/Hb
#define WSTR 204   // f32 row stride for w_s (16B-aligned f4s, 2-way banks = free)

__global__ __launch_bounds__(256) void trunk(TParams P) {
    __shared__ float w_s[16 * WSTR];
    __shared__ short Ha[16 * LSTR];
    __shared__ short Hb[16 * LSTR];

    const int tid = threadIdx.x;
    const int l = tid & 63, w = tid >> 6;
    const int row0 = blockIdx.x * 16;

    // stage w rows (16 x 200 f32, contiguous in global)
    {
        const f4* src = (const f4*)(P.w + (size_t)row0 * NT);
        for (int ch = tid; ch < 800; ch += 256) {
            int t = ch * 4;
            int r = t / NT, c = t - r * NT;     // c stays inside one row (200%4==0)
            *(f4*)&w_s[r * WSTR + c] = src[ch];
        }
    }
    __syncthreads();

    // interest[r][e4..e4+3] = sum_t w_s[r][t] * ub[b(r)][t][e4..]; then BN1
    {
        int r  = tid >> 4;
        int e4 = (tid & 15) * 4;
        int bb = (row0 + r) / NTQ;
        const f4* ub4 = (const f4*)(P.ub + (size_t)bb * NT * NE + e4);
        f4 s; s[0]=0.f; s[1]=0.f; s[2]=0.f; s[3]=0.f;
        #pragma unroll 8
        for (int t = 0; t < NT; ++t) {
            float wt = w_s[r * WSTR + t];
            f4 u = ub4[(size_t)t * (NE / 4)];
            s[0] = fmaf(wt, u[0], s[0]);
            s[1] = fmaf(wt, u[1], s[1]);
            s[2] = fmaf(wt, u[2], s[2]);
            s[3] = fmaf(wt, u[3], s[3]);
        }
        s4v hv;
        #pragma unroll
        for (int j = 0; j < 4; ++j) {
            int col = e4 + j;
            float hn = (s[j] - P.bn1_m[col]) * rsqrtf(P.bn1_v[col] + 1e-6f)
                       * P.bn1_g[col] + P.bn1_b[col];
            hv[j] = f2bf(hn);
        }
        *(s4v*)&Ha[r * LSTR + e4] = hv;
    }
    // stage cols 64..255 = bn1(profile || context)
    for (int ch = tid; ch < 16 * 192; ch += 256) {
        int r = ch / 192, c = ch % 192;
        int col = 64 + c;
        int b = (row0 + r) / NTQ;
        float val = (c < NP) ? P.up[b * NP + c] : P.cx[b * NC + (c - NP)];
        float hn = (val - P.bn1_m[col]) * rsqrtf(P.bn1_v[col] + 1e-6f)
                   * P.bn1_g[col] + P.bn1_b[col];
        Ha[r * LSTR + col] = f2bf(hn);
    }
    __syncthreads();

    const int ar = l & 15;            // A-frag row
    const int rl = 4 * (l >> 4);      // D row base
    const int nl = l & 15;            // D col within n-tile

    // ---- layer 1: K=256, N=256 : Ha -> Hb, relu then BN2 ----
    {
        bf8 a[8];
        #pragma unroll
        for (int ks = 0; ks < 8; ++ks)
            a[ks] = *(const bf8*)&Ha[ar * LSTR + ks * 32 + 8 * (l >> 4)];
        const bf8* wf = (const bf8*)P.wm1f;
        #pragma unroll
        for (int nt0 = 0; nt0 < 4; ++nt0) {
            int nt = w * 4 + nt0;
            f4 acc; acc[0]=0.f; acc[1]=0.f; acc[2]=0.f; acc[3]=0.f;
            #pragma unroll
            for (int ks = 0; ks < 8; ++ks)
                acc = __builtin_amdgcn_mfma_f32_16x16x32_bf16(a[ks], wf[(nt * 8 + ks) * 64 + l], acc, 0, 0, 0);
            int n = nt * 16 + nl;
            float g1 = P.bn2_g[n] * rsqrtf(P.bn2_v[n] + 1e-6f);
            float c1 = P.bn2_b[n] - P.bn2_m[n] * g1;
            float bias = P.bm1[n];
            #pragma unroll
            for (int i = 0; i < 4; ++i) {
                float v = fmaxf(acc[i] + bias, 0.f);
                Hb[(rl + i) * LSTR + n] = f2bf(v * g1 + c1);
            }
        }
    }
    __syncthreads();

    // ---- layer 2: K=256, N=128 : Hb -> Ha[:,0:128], relu then BN3 ----
    {
        bf8 a[8];
        #pragma unroll
        for (int ks = 0; ks < 8; ++ks)
            a[ks] = *(const bf8*)&Hb[ar * LSTR + ks * 32 + 8 * (l >> 4)];
        const bf8* wf = (const bf8*)P.wm2f;
        #pragma unroll
        for (int nt0 = 0; nt0 < 2; ++nt0) {
            int nt = w * 2 + nt0;
            f4 acc; acc[0]=0.f; acc[1]=0.f; acc[2]=0.f; acc[3]=0.f;
            #pragma unroll
            for (int ks = 0; ks < 8; ++ks)
                acc = __builtin_amdgcn_mfma_f32_16x16x32_bf16(a[ks], wf[(nt * 8 + ks) * 64 + l], acc, 0, 0, 0);
            int n = nt * 16 + nl;
            float g1 = P.bn3_g[n] * rsqrtf(P.bn3_v[n] + 1e-6f);
            float c1 = P.bn3_b[n] - P.bn3_m[n] * g1;
            float bias = P.bm2[n];
            #pragma unroll
            for (int i = 0; i < 4; ++i) {
                float v = fmaxf(acc[i] + bias, 0.f);
                Ha[(rl + i) * LSTR + n] = f2bf(v * g1 + c1);
            }
        }
    }
    __syncthreads();

    // ---- layer 3: K=128, N=64 : Ha[:,0:128] -> out, relu ----
    {
        bf8 a[4];
        #pragma unroll
        for (int ks = 0; ks < 4; ++ks)
            a[ks] = *(const bf8*)&Ha[ar * LSTR + ks * 32 + 8 * (l >> 4)];
        const bf8* wf = (const bf8*)P.wm3f;
        {
            int nt = w;
            f4 acc; acc[0]=0.f; acc[1]=0.f; acc[2]=0.f; acc[3]=0.f;
            #pragma unroll
            for (int ks = 0; ks < 4; ++ks)
                acc = __builtin_amdgcn_mfma_f32_16x16x32_bf16(a[ks], wf[(nt * 4 + ks) * 64 + l], acc, 0, 0, 0);
            int n = nt * 16 + nl;
            float bias = P.bm3[n];
            #pragma unroll
            for (int i = 0; i < 4; ++i)
                P.out[(size_t)(row0 + rl + i) * 64 + n] = fmaxf(acc[i] + bias, 0.f);
        }
    }
}

// ---------------------------------------------------------------------------
extern "C" void kernel_launch(void* const* d_in, const int* in_sizes, int n_in,
                              void* d_out, int out_size, void* d_ws, size_t ws_size,
                              hipStream_t stream) {
    (void)in_sizes; (void)n_in; (void)out_size; (void)ws_size;

    const float* ub         = (const float*)d_in[0];
    const float* it         = (const float*)d_in[1];
    const float* up         = (const float*)d_in[2];
    const float* cx         = (const float*)d_in[3];
    const float* W1         = (const float*)d_in[4];
    const float* b1         = (const float*)d_in[5];
    const float* dice_alpha = (const float*)d_in[6];
    const float* dice_mean  = (const float*)d_in[7];
    const float* dice_var   = (const float*)d_in[8];
    const float* W2         = (const float*)d_in[9];
    const float* b2         = (const float*)d_in[10];
    const float* bn1_g      = (const float*)d_in[11];
    const float* bn1_b      = (const float*)d_in[12];
    const float* bn1_m      = (const float*)d_in[13];
    const float* bn1_v      = (const float*)d_in[14];
    const float* Wm1        = (const float*)d_in[15];
    const float* bm1        = (const float*)d_in[16];
    const float* bn2_g      = (const float*)d_in[17];
    const float* bn2_b      = (const float*)d_in[18];
    const float* bn2_m      = (const float*)d_in[19];
    const float* bn2_v      = (const float*)d_in[20];
    const float* Wm2        = (const float*)d_in[21];
    const float* bm2        = (const float*)d_in[22];
    const float* bn3_g      = (const float*)d_in[23];
    const float* bn3_b      = (const float*)d_in[24];
    const float* bn3_m      = (const float*)d_in[25];
    const float* bn3_v      = (const float*)d_in[26];
    const float* Wm3        = (const float*)d_in[27];
    const float* bm3        = (const float*)d_in[28];

    short* wsb  = (short*)d_ws;
    short* wm1f = wsb + WM1F_OFF;
    short* wm2f = wsb + WM2F_OFF;
    short* wm3f = wsb + WM3F_OFF;
    short* w1f  = wsb + W1F_OFF;
    float* kW   = (float*)((char*)d_ws + KW_BYTE);
    float* wbuf = (float*)((char*)d_ws + W_BYTE);

    const int prep_total = NROW * NU + 6144;   // 63744 -> 249 blocks
    prep<<<(prep_total + 255) / 256, 256, 0, stream>>>(it, W1, b1, kW, w1f);

    AParams A;
    A.ub = ub; A.it = it; A.kW = kW;
    A.W2 = W2; A.b2 = b2; A.da = dice_alpha; A.dm = dice_mean; A.dv = dice_var;
    A.Wm1 = Wm1; A.Wm2 = Wm2; A.Wm3 = Wm3;
    A.w1f = w1f; A.wm1f = wm1f; A.wm2f = wm2f; A.wm3f = wm3f;
    A.w = wbuf;
    attn2<<<ATTN_BLOCKS + PACK_BLOCKS, 256, 0, stream>>>(A);

    TParams T;
    T.w = wbuf; T.ub = ub; T.up = up; T.cx = cx;
    T.wm1f = wm1f; T.wm2f = wm2f; T.wm3f = wm3f;
    T.bn1_g = bn1_g; T.bn1_b = bn1_b; T.bn1_m = bn1_m; T.bn1_v = bn1_v;
    T.bm1 = bm1; T.bm2 = bm2; T.bm3 = bm3;
    T.bn2_g = bn2_g; T.bn2_b = bn2_b; T.bn2_m = bn2_m; T.bn2_v = bn2_v;
    T.bn3_g = bn3_g; T.bn3_b = bn3_b; T.bn3_m = bn3_m; T.bn3_v = bn3_v;
    T.out = (float*)d_out;
    trunk<<<NROW / 16, 256, 0, stream>>>(T);
}